// Round 3
// baseline (6563.808 us; speedup 1.0000x reference)
//
#include <hip/hip_runtime.h>
#include <cstdint>

#define B_  64
#define T_  4096
#define F_  100
#define H_  200
#define G_  600   // 3H
#define KP_ 224   // K (=H) padded to 4 x 56 for 16B-aligned quarter-slices
#define KH_ 112   // KP_/2 half2 rows in packed Wh

typedef _Float16 half2_t __attribute__((ext_vector_type(2)));

__device__ __forceinline__ float sigmoidf_(float x) {
    return 1.0f / (1.0f + __expf(-x));
}
__device__ __forceinline__ float tanh_fast_(float x) {
    float e = __expf(-2.0f * x);
    return (1.0f - e) / (1.0f + e);
}

__device__ __forceinline__ float fdot2_(half2_t a, half2_t b, float c) {
#if __has_builtin(__builtin_amdgcn_fdot2)
    return __builtin_amdgcn_fdot2(a, b, c, false);
#else
    return fmaf((float)a.x, (float)b.x, fmaf((float)a.y, (float)b.y, c));
#endif
}

// quad (4-lane) butterfly sum via DPP quad_perm — pure VALU, no LDS pipe.
__device__ __forceinline__ float quad_sum_(float x) {
    int y1 = __builtin_amdgcn_update_dpp(0, __float_as_int(x), 0xB1, 0xF, 0xF, true); // [1,0,3,2]
    x += __int_as_float(y1);
    int y2 = __builtin_amdgcn_update_dpp(0, __float_as_int(x), 0x4E, 0xF, 0xF, true); // [2,3,0,1]
    return x + __int_as_float(y2);
}
// broadcast lane 2 of each quad to all 4 lanes
__device__ __forceinline__ float quad_bcast2_(float x) {
    int y = __builtin_amdgcn_update_dpp(0, __float_as_int(x), 0xAA, 0xF, 0xF, true); // [2,2,2,2]
    return __int_as_float(y);
}

// ---------------- Phase 0: pack Wh (f32 [200,600]) -> half2 [112][600] ----------------
// whp[k*600 + c] = (Wh[2k][c], Wh[2k+1][c]); rows 100..111 zero (K padded 200->224)
__global__ void prep_whp(const float* __restrict__ Wh, half2_t* __restrict__ whp) {
    int i = blockIdx.x * 256 + threadIdx.x;
    if (i < KH_ * G_) {
        int k = i / G_, c = i - k * G_;
        half2_t v;
        v.x = (k < 100) ? (_Float16)Wh[(2 * k) * G_ + c] : (_Float16)0.f;
        v.y = (k < 100) ? (_Float16)Wh[(2 * k + 1) * G_ + c] : (_Float16)0.f;
        whp[i] = v;
    }
}

// ---------------- Phase 1: gi = x @ Wi + bi (fp32) ----------------
// Session-verified 640-thread structure; store layout now GATE-INTERLEAVED:
// gi[row*600 + e*3 + gate] so the scan's per-quad prefetch (lanes s=0..2 read
// gates r,z,n of element e) is a coalesced 12B read.
__global__ __launch_bounds__(640, 1)
void gi_kernel(const float* __restrict__ x, const float* __restrict__ Wi,
               const float* __restrict__ bi, float* __restrict__ gi,
               int t0, int TC) {
    __shared__ float xT[F_ * 68];
    int row0 = blockIdx.x * 64;
    int b    = row0 / TC;
    int tc0  = row0 - b * TC;
    const float* xrow = x + ((size_t)b * T_ + t0 + tc0) * F_;
    for (int i = threadIdx.x; i < 64 * F_; i += 640) {
        int r = i / F_, f = i - r * F_;
        xT[f * 68 + r] = xrow[i];
    }
    __syncthreads();
    int col = threadIdx.x < G_ ? threadIdx.x : G_ - 1;
    float acc[64];
    #pragma unroll
    for (int r = 0; r < 64; ++r) acc[r] = 0.f;
    for (int f = 0; f < F_; ++f) {
        float wi = Wi[f * G_ + col];
        const float4* xf = (const float4*)&xT[f * 68];
        #pragma unroll
        for (int q = 0; q < 16; ++q) {
            float4 v = xf[q];
            acc[4*q+0] = fmaf(v.x, wi, acc[4*q+0]);
            acc[4*q+1] = fmaf(v.y, wi, acc[4*q+1]);
            acc[4*q+2] = fmaf(v.z, wi, acc[4*q+2]);
            acc[4*q+3] = fmaf(v.w, wi, acc[4*q+3]);
        }
    }
    if (threadIdx.x < G_) {
        int gate = col / H_;
        int e    = col - gate * H_;
        float bv = bi[col];
        float* grow = gi + (size_t)row0 * G_ + (size_t)e * 3 + gate;
        #pragma unroll 4
        for (int r = 0; r < 64; ++r) grow[(size_t)r * G_] = acc[r] + bv;
    }
}

// ---------------- Phase 2: sequential GRU scan ----------------
// 64 blocks (one per batch), 832 threads (13 waves). Quad 4p..4p+3 owns
// h-element p; lane s=tid&3 covers K-quarter [56s,56s+56) of ALL THREE gate
// columns {p, 200+p, 400+p}. Weights: 3 x 28 = 84 half2 regs/thread;
// amdgpu_waves_per_eu(4) caps arch VGPR at 128 so they stay in arch VGPRs
// (round-2's VGPR_Count=72 showed AGPR placement, costing ~1 extra move per
// fdot2 — the measured 2.3x VALU inflation).
// LDS h-broadcast: 13 waves x 7 ds_read_b128 = 91 wave-instrs/step (vs 130),
// each 16B chunk reused for 3 dots. Quad DPP butterfly gives every lane the
// full r,z,n sums -> elementwise fused in-thread, NO A_lds round-trip, and
// double-buffered h gives exactly ONE barrier per step (vs 2).
__global__ __launch_bounds__(832, 1) __attribute__((amdgpu_waves_per_eu(4)))
void scan_kernel(const float* __restrict__ gi, const half2_t* __restrict__ whp,
                 const float* __restrict__ bhn, _Float16* __restrict__ hs,
                 float* __restrict__ hstate, int TC, int first) {
    __shared__ __align__(16) _Float16 h_h[2][KP_];   // double-buffered h (f16)
    int b = blockIdx.x;
    int tid = threadIdx.x;
    int p = tid >> 2;                 // h-element, [0,208)
    int s = tid & 3;                  // K-quarter
    int pc = p < H_ ? p : H_ - 1;     // clamp: quads 200..207 duplicate, never write
    bool writer = (s == 0 && p < H_);

    half2_t wr[28], wz[28], wn[28];   // 84 VGPRs of packed f16 weights
    const half2_t* wbase = whp + (size_t)(28 * s) * G_;
    #pragma unroll
    for (int j = 0; j < 28; ++j) {
        wr[j] = wbase[(size_t)j * G_ + pc];
        wz[j] = wbase[(size_t)j * G_ + H_ + pc];
        wn[j] = wbase[(size_t)j * G_ + 2 * H_ + pc];
    }
    float bhn_r = (s == 2) ? bhn[pc] : 0.f;   // folded once into n-dot partial

    float hj = first ? 0.f : hstate[b * H_ + pc];   // all lanes keep h[p]
    if (writer) h_h[0][p] = (_Float16)hj;
    if (tid < KP_ - H_) {                           // zero K-padding, both buffers
        h_h[0][H_ + tid] = (_Float16)0.f;
        h_h[1][H_ + tid] = (_Float16)0.f;
    }
    __syncthreads();

    const float* girow = gi + (size_t)b * TC * G_;
    _Float16* hsb = hs + (size_t)b * TC * H_;

    int p3 = pc * 3;
    float g = (s < 3) ? girow[p3 + s] : 0.f;        // lane s holds gate-s gi
    int cur = 0;
    for (int tc = 0; tc < TC; ++tc) {
        float gnx = (s < 3 && tc + 1 < TC)
                  ? girow[(size_t)(tc + 1) * G_ + p3 + s] : 0.f;   // prefetch
        // K-quarter partial dots, h broadcast from LDS (7 x b128, reused x3)
        float r0 = 0.f, r1 = 0.f, z0 = 0.f, z1 = 0.f, n0 = 0.f, n1 = 0.f;
        const float4* h4 = (const float4*)(&h_h[cur][0]) + 7 * s;
        #pragma unroll
        for (int q = 0; q < 7; ++q) {
            float4 hv = h4[q];
            half2_t* hp = (half2_t*)&hv;
            r0 = fdot2_(hp[0], wr[4*q+0], r0);
            z0 = fdot2_(hp[0], wz[4*q+0], z0);
            n0 = fdot2_(hp[0], wn[4*q+0], n0);
            r1 = fdot2_(hp[1], wr[4*q+1], r1);
            z1 = fdot2_(hp[1], wz[4*q+1], z1);
            n1 = fdot2_(hp[1], wn[4*q+1], n1);
            r0 = fdot2_(hp[2], wr[4*q+2], r0);
            z0 = fdot2_(hp[2], wz[4*q+2], z0);
            n0 = fdot2_(hp[2], wn[4*q+2], n0);
            r1 = fdot2_(hp[3], wr[4*q+3], r1);
            z1 = fdot2_(hp[3], wz[4*q+3], z1);
            n1 = fdot2_(hp[3], wn[4*q+3], n1);
        }
        float pr = r0 + r1, pz = z0 + z1, pn = n0 + n1;
        pr += (s == 0) ? g : 0.f;     // fold gi_r once
        pz += (s == 1) ? g : 0.f;     // fold gi_z once
        pn += bhn_r;                  // fold bhn once (lane 2); INSIDE r*(...) term
        // quad butterfly: every lane gets full R, Z, N for its h-element
        float R = quad_sum_(pr);
        float Z = quad_sum_(pz);
        float N = quad_sum_(pn);
        float gn = quad_bcast2_(g);   // gi_n from lane 2 (OUTSIDE r*(...))
        float rr = sigmoidf_(R);
        float zz = sigmoidf_(Z);
        float nn = tanh_fast_(gn + rr * N);
        hj = nn + zz * (hj - nn);     // all 4 lanes redundantly
        if (writer) {
            h_h[cur ^ 1][p] = (_Float16)hj;
            hsb[(size_t)tc * H_ + p] = (_Float16)hj;   // fire-and-forget
        }
        __syncthreads();              // ONE barrier per step (double-buffered h)
        g = gnx;
        cur ^= 1;
    }
    if (writer) hstate[b * H_ + p] = hj;
}

// ---------------- Phase 3: out = hs @ Wo + bo ----------------
__global__ __launch_bounds__(256, 4)
void outproj_kernel(const _Float16* __restrict__ hs, const float* __restrict__ Wo,
                    const float* __restrict__ bo, float* __restrict__ out,
                    int t0, int TC) {
    int r = blockIdx.x * 256 + threadIdx.x;
    if (r >= B_ * TC) return;
    int b = r / TC, tc = r - b * TC;
    const float4* h4 = (const float4*)(hs + (size_t)r * H_);
    float acc = 0.f;
    #pragma unroll
    for (int q = 0; q < 25; ++q) {
        float4 v = h4[q];
        const _Float16* hp = (const _Float16*)&v;
        #pragma unroll
        for (int j = 0; j < 8; ++j)
            acc = fmaf((float)hp[j], Wo[q * 8 + j], acc);
    }
    out[(size_t)b * T_ + t0 + tc] = acc + bo[0];
}

extern "C" void kernel_launch(void* const* d_in, const int* in_sizes, int n_in,
                              void* d_out, int out_size, void* d_ws, size_t ws_size,
                              hipStream_t stream) {
    const float* x   = (const float*)d_in[0];
    const float* Wi  = (const float*)d_in[1];
    const float* bi  = (const float*)d_in[2];
    const float* Wh  = (const float*)d_in[3];
    const float* bhn = (const float*)d_in[4];
    const float* Wo  = (const float*)d_in[5];
    const float* bo  = (const float*)d_in[6];
    float* out = (float*)d_out;

    const size_t hstate_b = (size_t)B_ * H_ * sizeof(float);
    const size_t whp_b    = (size_t)KH_ * G_ * sizeof(half2_t);
    // ws layout: [gi: B*TC*G*4][hs: B*TC*H*2][hstate][whp]
    int TC = T_;
    while (TC > 64 &&
           (size_t)B_ * TC * (G_ * 4 + H_ * 2) + hstate_b + whp_b > ws_size)
        TC >>= 1;
    char* p = (char*)d_ws;
    float*    gi     = (float*)p;            p += (size_t)B_ * TC * G_ * sizeof(float);
    _Float16* hsbuf  = (_Float16*)p;         p += (size_t)B_ * TC * H_ * sizeof(_Float16);
    float*    hstate = (float*)p;            p += hstate_b;
    half2_t*  whp    = (half2_t*)p;

    prep_whp<<<dim3((KH_ * G_ + 255) / 256), dim3(256), 0, stream>>>(Wh, whp);

    int nchunks = T_ / TC;
    for (int c = 0; c < nchunks; ++c) {
        int t0 = c * TC;
        gi_kernel<<<dim3(B_ * TC / 64), dim3(640), 0, stream>>>(x, Wi, bi, gi, t0, TC);
        scan_kernel<<<dim3(B_), dim3(832), 0, stream>>>(gi, whp, bhn, hsbuf,
                                                        hstate, TC, c == 0);
        outproj_kernel<<<dim3((B_ * TC + 255) / 256), dim3(256), 0, stream>>>(
            hsbuf, Wo, bo, out, t0, TC);
    }
}